// Round 9
// baseline (670.749 us; speedup 1.0000x reference)
//
#include <hip/hip_runtime.h>
#include <hip/hip_bf16.h>
#include <cstdint>

typedef __bf16 bf16;
typedef __bf16 bf16x8 __attribute__((ext_vector_type(8)));
typedef __bf16 bf16x4 __attribute__((ext_vector_type(4)));
typedef float  f32x4  __attribute__((ext_vector_type(4)));

constexpr int V_    = 32000;
constexpr int SMAX_ = 1024;
constexpr int D_    = 1024;
constexpr int H_    = 16;
constexpr int L_    = 2;
constexpr int DFF_  = 4096;
constexpr int WIN_  = 256;
constexpr int B_    = 2;
constexpr int M_    = B_ * SMAX_; // 2048

#define SBAR0_() __builtin_amdgcn_sched_barrier(0)
#define HWBAR_() { __builtin_amdgcn_s_barrier(); SBAR0_(); }
#define LGKM0_() { asm volatile("s_waitcnt lgkmcnt(0)" ::: "memory"); SBAR0_(); }
#define VM0_()   { asm volatile("s_waitcnt vmcnt(0)" ::: "memory"); SBAR0_(); }
#define VM4_()   { asm volatile("s_waitcnt vmcnt(4)" ::: "memory"); SBAR0_(); }

// ---------------------------------------------------------------------------
// LM head: 256x256, 8 waves (2Mx4N, wave 128x64), BK=64, 0-conflict
// slot^=(row&7) layout. ASYMMETRIC buffering: A 2-buf (prefetch dist 1),
// B 3-buf (dist 2) -> counted vmcnt(4) at each tile, NEVER drains to 0
// (T4). 4 fine phases/K-tile (ks x n-half quadrants, A-frags reused):
// {ds_read, 2-load stage, lgkm0, setprio 16 MFMA, bar}. LDS 160 KB.
// ---------------------------------------------------------------------------
__global__ __launch_bounds__(512, 1) void gemm_lm4(
    const bf16* __restrict__ A, const bf16* __restrict__ BT,
    float* __restrict__ outf, int Nn)
{
  constexpr int KK = 1024, NT = 16;
  __shared__ __align__(16) bf16 ldsA[2][16384];   // 2 x 256 rows x 64
  __shared__ __align__(16) bf16 ldsB[3][16384];   // 3 x 256 rows x 64

  const int t = threadIdx.x, lane = t & 63, w = t >> 6;
  const int l16 = lane & 15, lh = lane >> 4;
  const int wm = w >> 2, wn = w & 3;              // 2M x 4N

  const int nloc = gridDim.x >> 3;                // 1000/8 = 125
  const int wg = (blockIdx.x & 7) * nloc + (blockIdx.x >> 3);
  const long m0 = (long)(wg & 7) * 256;
  const long n0 = (long)(wg >> 3) * 256;

  // stage 64 rows (8KB, 1 load/thread) of a 256x64 tile; linear dest,
  // inverse-swizzled source slot (phys slot t&7 holds logical (t&7)^(row&7)).
  auto SA = [&](int c, int k0, int q) {
    int row = q * 64 + (t >> 3);
    int sl  = (t & 7) ^ (row & 7);
    const bf16* g = A + (m0 + row) * (long)KK + k0 + sl * 8;
    __builtin_amdgcn_global_load_lds(
        (const __attribute__((address_space(1))) uint32_t*)g,
        (__attribute__((address_space(3))) uint32_t*)(&ldsA[c][q * 4096 + t * 8]),
        16, 0, 0);
  };
  auto SB = [&](int c, int k0, int q) {
    int row = q * 64 + (t >> 3);
    int sl  = (t & 7) ^ (row & 7);
    const bf16* g = BT + (n0 + row) * (long)KK + k0 + sl * 8;
    __builtin_amdgcn_global_load_lds(
        (const __attribute__((address_space(1))) uint32_t*)g,
        (__attribute__((address_space(3))) uint32_t*)(&ldsB[c][q * 4096 + t * 8]),
        16, 0, 0);
  };
  auto LDA = [&](int c, int mi, int ks) -> bf16x8 {
    int row = wm * 128 + mi * 16 + l16;
    int sl  = (ks * 4 + lh) ^ (row & 7);
    return *(const bf16x8*)(&ldsA[c][row * 64 + sl * 8]);
  };
  auto LDB = [&](int c, int ni, int ks) -> bf16x8 {
    int row = wn * 64 + ni * 16 + l16;
    int sl  = (ks * 4 + lh) ^ (row & 7);
    return *(const bf16x8*)(&ldsB[c][row * 64 + sl * 8]);
  };

  f32x4 acc[8][4] = {};
  bf16x8 a[8], b0, b1;

  // prologue queue: [A0:4, B0:4, B1:4]
  #pragma unroll
  for (int q = 0; q < 4; ++q) SA(0, 0, q);
  #pragma unroll
  for (int q = 0; q < 4; ++q) SB(0, 0, q);
  #pragma unroll
  for (int q = 0; q < 4; ++q) SB(1, 64, q);

  for (int j = 0; j < NT; ++j) {
    const int cA = j & 1, cAn = cA ^ 1;
    const int cB = j % 3, cBn = (j + 2) % 3;
    const int kA = ((j + 1) & (NT - 1)) * 64;     // A(j+1)
    const int kB = ((j + 2) & (NT - 1)) * 64;     // B(j+2)
    // entering: queue = [A(j):4, B(j+1):4]; vmcnt(4) -> A(j),B(j) landed,
    // B(j+1) stays in flight. Never drains.
    VM4_();
    HWBAR_();
    // ---- P1: ks0 x n{0,1} ----
    #pragma unroll
    for (int mi = 0; mi < 8; ++mi) a[mi] = LDA(cA, mi, 0);
    b0 = LDB(cB, 0, 0); b1 = LDB(cB, 1, 0);
    SA(cAn, kA, 0); SA(cAn, kA, 1);
    LGKM0_();
    __builtin_amdgcn_s_setprio(1);
    #pragma unroll
    for (int mi = 0; mi < 8; ++mi) {
      acc[mi][0] = __builtin_amdgcn_mfma_f32_16x16x32_bf16(a[mi], b0, acc[mi][0], 0, 0, 0);
      acc[mi][1] = __builtin_amdgcn_mfma_f32_16x16x32_bf16(a[mi], b1, acc[mi][1], 0, 0, 0);
    }
    __builtin_amdgcn_s_setprio(0);
    HWBAR_();
    // ---- P2: ks0 x n{2,3} (A-frags reused) ----
    b0 = LDB(cB, 2, 0); b1 = LDB(cB, 3, 0);
    SA(cAn, kA, 2); SA(cAn, kA, 3);
    LGKM0_();
    __builtin_amdgcn_s_setprio(1);
    #pragma unroll
    for (int mi = 0; mi < 8; ++mi) {
      acc[mi][2] = __builtin_amdgcn_mfma_f32_16x16x32_bf16(a[mi], b0, acc[mi][2], 0, 0, 0);
      acc[mi][3] = __builtin_amdgcn_mfma_f32_16x16x32_bf16(a[mi], b1, acc[mi][3], 0, 0, 0);
    }
    __builtin_amdgcn_s_setprio(0);
    HWBAR_();
    // ---- P3: ks1 x n{0,1} ----
    #pragma unroll
    for (int mi = 0; mi < 8; ++mi) a[mi] = LDA(cA, mi, 1);
    b0 = LDB(cB, 0, 1); b1 = LDB(cB, 1, 1);
    SB(cBn, kB, 0); SB(cBn, kB, 1);
    LGKM0_();
    __builtin_amdgcn_s_setprio(1);
    #pragma unroll
    for (int mi = 0; mi < 8; ++mi) {
      acc[mi][0] = __builtin_amdgcn_mfma_f32_16x16x32_bf16(a[mi], b0, acc[mi][0], 0, 0, 0);
      acc[mi][1] = __builtin_amdgcn_mfma_f32_16x16x32_bf16(a[mi], b1, acc[mi][1], 0, 0, 0);
    }
    __builtin_amdgcn_s_setprio(0);
    HWBAR_();
    // ---- P4: ks1 x n{2,3} ----
    b0 = LDB(cB, 2, 1); b1 = LDB(cB, 3, 1);
    SB(cBn, kB, 2); SB(cBn, kB, 3);
    LGKM0_();
    __builtin_amdgcn_s_setprio(1);
    #pragma unroll
    for (int mi = 0; mi < 8; ++mi) {
      acc[mi][2] = __builtin_amdgcn_mfma_f32_16x16x32_bf16(a[mi], b0, acc[mi][2], 0, 0, 0);
      acc[mi][3] = __builtin_amdgcn_mfma_f32_16x16x32_bf16(a[mi], b1, acc[mi][3], 0, 0, 0);
    }
    __builtin_amdgcn_s_setprio(0);
  }

  asm volatile("s_waitcnt vmcnt(0) lgkmcnt(0)" ::: "memory");
  #pragma unroll
  for (int mi = 0; mi < 8; ++mi)
    #pragma unroll
    for (int ni = 0; ni < 4; ++ni)
      #pragma unroll
      for (int rr = 0; rr < 4; ++rr) {
        long row = m0 + wm * 128 + mi * 16 + lh * 4 + rr;
        long col = n0 + wn * 64 + ni * 16 + l16;
        outf[row * Nn + col] = acc[mi][ni][rr];
      }
}

// ---------------------------------------------------------------------------
// Layer GEMMs: BM x 128 tile, BK=64 conflict-free layout, 4 waves (2Mx2N),
// 2 LDS buffers, stage-both-in-phase-0.  (unchanged from round 8)
// EPI: 0 bias->bf16, 1 bias+gelu->bf16, 2 bias+residual->f32, 3 ->f32
// ---------------------------------------------------------------------------
template<int BM, int EPI>
__global__ __launch_bounds__(256) void gemm_l2(
    const bf16* __restrict__ A, const bf16* __restrict__ BT,
    const float* __restrict__ bias, float* __restrict__ resid,
    bf16* __restrict__ outb, float* __restrict__ outf,
    int Nn, int Kk, int nbyMask, int nbyShift)
{
  constexpr int MR = BM / 32;
  constexpr int CA = BM / 32;
  __shared__ __align__(16) bf16 ldsA[2][BM * 64];
  __shared__ __align__(16) bf16 ldsB[2][8192];

  const int t = threadIdx.x, lane = t & 63, w = t >> 6;
  const int l16 = lane & 15, lh = lane >> 4;
  const int wm = w >> 1, wn = w & 1;

  const int nwg = gridDim.x, bid = blockIdx.x;
  const int nloc = nwg >> 3;
  const int wg = (bid & 7) * nloc + (bid >> 3);
  const long m0 = (long)(wg & nbyMask) * BM;
  const long n0 = (long)(wg >> nbyShift) * 128;

  auto STGA = [&](int c, int k0) {
    #pragma unroll
    for (int q = 0; q < CA; ++q) {
      int row = q * 32 + (t >> 3);
      int sl  = (t & 7) ^ (row & 7);
      const bf16* g = A + (m0 + row) * (long)Kk + k0 + sl * 8;
      __builtin_amdgcn_global_load_lds(
          (const __attribute__((address_space(1))) uint32_t*)g,
          (__attribute__((address_space(3))) uint32_t*)(&ldsA[c][q * 2048 + t * 8]),
          16, 0, 0);
    }
  };
  auto STGB = [&](int c, int k0) {
    #pragma unroll
    for (int q = 0; q < 4; ++q) {
      int row = q * 32 + (t >> 3);
      int sl  = (t & 7) ^ (row & 7);
      const bf16* g = BT + (n0 + row) * (long)Kk + k0 + sl * 8;
      __builtin_amdgcn_global_load_lds(
          (const __attribute__((address_space(1))) uint32_t*)g,
          (__attribute__((address_space(3))) uint32_t*)(&ldsB[c][q * 2048 + t * 8]),
          16, 0, 0);
    }
  };
  auto LDA = [&](int c, int mi, int ks) -> bf16x8 {
    int row = wm * (BM / 2) + mi * 16 + l16;
    int sl  = (ks * 4 + lh) ^ (row & 7);
    return *(const bf16x8*)(&ldsA[c][row * 64 + sl * 8]);
  };
  auto LDB = [&](int c, int ni, int ks) -> bf16x8 {
    int row = wn * 64 + ni * 16 + l16;
    int sl  = (ks * 4 + lh) ^ (row & 7);
    return *(const bf16x8*)(&ldsB[c][row * 64 + sl * 8]);
  };

  f32x4 acc[MR][4] = {};
  bf16x8 a[MR], b[4];

  STGA(0, 0); STGB(0, 0);
  int kNext = 64;

  const int NT = Kk >> 6;
  for (int j = 0; j < NT; ++j) {
    const int c = j & 1;
    VM0_();
    HWBAR_();
    #pragma unroll
    for (int mi = 0; mi < MR; ++mi) a[mi] = LDA(c, mi, 0);
    #pragma unroll
    for (int ni = 0; ni < 4; ++ni) b[ni] = LDB(c, ni, 0);
    STGA(c ^ 1, kNext); STGB(c ^ 1, kNext);
    LGKM0_();
    __builtin_amdgcn_s_setprio(1);
    #pragma unroll
    for (int mi = 0; mi < MR; ++mi)
      #pragma unroll
      for (int ni = 0; ni < 4; ++ni)
        acc[mi][ni] = __builtin_amdgcn_mfma_f32_16x16x32_bf16(a[mi], b[ni], acc[mi][ni], 0, 0, 0);
    __builtin_amdgcn_s_setprio(0);
    HWBAR_();
    #pragma unroll
    for (int mi = 0; mi < MR; ++mi) a[mi] = LDA(c, mi, 1);
    #pragma unroll
    for (int ni = 0; ni < 4; ++ni) b[ni] = LDB(c, ni, 1);
    LGKM0_();
    __builtin_amdgcn_s_setprio(1);
    #pragma unroll
    for (int mi = 0; mi < MR; ++mi)
      #pragma unroll
      for (int ni = 0; ni < 4; ++ni)
        acc[mi][ni] = __builtin_amdgcn_mfma_f32_16x16x32_bf16(a[mi], b[ni], acc[mi][ni], 0, 0, 0);
    __builtin_amdgcn_s_setprio(0);
    kNext += 64; if (kNext == Kk) kNext = 0;
  }

  #pragma unroll
  for (int mi = 0; mi < MR; ++mi)
    #pragma unroll
    for (int ni = 0; ni < 4; ++ni)
      #pragma unroll
      for (int rr = 0; rr < 4; ++rr) {
        long row = m0 + wm * (BM / 2) + mi * 16 + lh * 4 + rr;
        long col = n0 + wn * 64 + ni * 16 + l16;
        float v = acc[mi][ni][rr];
        if (EPI == 0) {
          outb[row * Nn + col] = (bf16)(v + bias[col]);
        } else if (EPI == 1) {
          float xx = v + bias[col];
          outb[row * Nn + col] = (bf16)(0.5f * xx * (1.0f + erff(xx * 0.70710678118654752f)));
        } else if (EPI == 2) {
          resid[row * Nn + col] += v + bias[col];
        } else {
          outf[row * Nn + col] = v;
        }
      }
}

// ---------------------------------------------------------------------------
// Sliding-window causal flash attention (unchanged).
// ---------------------------------------------------------------------------
__global__ __launch_bounds__(256) void attn_swa(
    const bf16* __restrict__ qkv, bf16* __restrict__ o)
{
  constexpr int PADK = 72;
  constexpr int PADV = 40;
  __shared__ bf16 Qs[64 * PADK];
  __shared__ bf16 Ks[32 * PADK];
  __shared__ bf16 Vt[64 * PADV];
  __shared__ bf16 Ps[4][16 * PADV];

  const int bid = blockIdx.x;
  const int qb = bid & 15;
  const int h  = (bid >> 4) & 15;
  const int b  = bid >> 8;
  const int q0 = qb * 64;
  const int t = threadIdx.x, lane = t & 63, w = t >> 6;
  const int l16 = lane & 15, lh = lane >> 4;

  #pragma unroll
  for (int i = 0; i < 2; i++) {
    int e = t + i * 256;
    int row = e >> 3, cc = e & 7;
    uint4 g = *(const uint4*)(qkv + ((long)(b * SMAX_ + q0 + row)) * 3072 + h * 64 + cc * 8);
    *(uint4*)(Qs + row * PADK + cc * 8) = g;
  }
  __syncthreads();
  bf16x8 aq[2];
  const int qrow = w * 16 + l16;
  #pragma unroll
  for (int ks = 0; ks < 2; ks++)
    aq[ks] = *(const bf16x8*)(Qs + qrow * PADK + ks * 32 + lh * 8);

  float m_run[4], l_run[4];
  f32x4 oacc[4];
  #pragma unroll
  for (int rr = 0; rr < 4; rr++) { m_run[rr] = -1e30f; l_run[rr] = 0.0f; }
  #pragma unroll
  for (int n = 0; n < 4; n++) oacc[n] = (f32x4){0.f, 0.f, 0.f, 0.f};

  const int tlo = q0 - (WIN_ - 1);
  const int jlo = (tlo <= 0) ? 0 : (tlo & ~31);
  const int iq  = q0 + w * 16 + lh * 4;

  for (int j0 = jlo; j0 < q0 + 64; j0 += 32) {
    __syncthreads();
    {
      int row = t >> 3, cc = t & 7;
      long base = ((long)(b * SMAX_ + j0 + row)) * 3072 + h * 64 + cc * 8;
      uint4 gk = *(const uint4*)(qkv + base + 1024);
      *(uint4*)(Ks + row * PADK + cc * 8) = gk;
      bf16x8 vv = *(const bf16x8*)(qkv + base + 2048);
      #pragma unroll
      for (int j = 0; j < 8; j++)
        Vt[(cc * 8 + j) * PADV + row] = vv[j];
    }
    __syncthreads();

    f32x4 s[2] = {(f32x4){0.f,0.f,0.f,0.f}, (f32x4){0.f,0.f,0.f,0.f}};
    #pragma unroll
    for (int nt = 0; nt < 2; nt++)
      #pragma unroll
      for (int ks = 0; ks < 2; ks++) {
        bf16x8 bk = *(const bf16x8*)(Ks + (nt * 16 + l16) * PADK + ks * 32 + lh * 8);
        s[nt] = __builtin_amdgcn_mfma_f32_16x16x32_bf16(aq[ks], bk, s[nt], 0, 0, 0);
      }

    float sc[2][4];
    #pragma unroll
    for (int nt = 0; nt < 2; nt++)
      #pragma unroll
      for (int rr = 0; rr < 4; rr++) {
        int i = iq + rr;
        int j = j0 + nt * 16 + l16;
        float v = s[nt][rr] * 0.125f;
        bool ok = (j <= i) && (i - j < WIN_);
        sc[nt][rr] = ok ? v : -1e30f;
      }

    float pb[2][4], alpha[4];
    #pragma unroll
    for (int rr = 0; rr < 4; rr++) {
      float mt = fmaxf(sc[0][rr], sc[1][rr]);
      #pragma unroll
      for (int off = 1; off < 16; off <<= 1) mt = fmaxf(mt, __shfl_xor(mt, off, 64));
      float mn = fmaxf(m_run[rr], mt);
      float a = __expf(m_run[rr] - mn);
      m_run[rr] = mn; alpha[rr] = a;
      float p0 = __expf(sc[0][rr] - mn);
      float p1 = __expf(sc[1][rr] - mn);
      pb[0][rr] = p0; pb[1][rr] = p1;
      float ls = p0 + p1;
      #pragma unroll
      for (int off = 1; off < 16; off <<= 1) ls += __shfl_xor(ls, off, 64);
      l_run[rr] = l_run[rr] * a + ls;
    }
    #pragma unroll
    for (int n = 0; n < 4; n++)
      #pragma unroll
      for (int rr = 0; rr < 4; rr++) oacc[n][rr] *= alpha[rr];

    #pragma unroll
    for (int rr = 0; rr < 4; rr++) {
      int prow = lh * 4 + rr;
      Ps[w][prow * PADV + l16]      = (bf16)pb[0][rr];
      Ps[w][prow * PADV + 16 + l16] = (bf16)pb[1][rr];
    }
    __syncthreads();

    bf16x8 pa = *(const bf16x8*)(&Ps[w][l16 * PADV + lh * 8]);
    #pragma unroll
    for (int n = 0; n < 4; n++) {
      bf16x8 bv = *(const bf16x8*)(Vt + (n * 16 + l16) * PADV + lh * 8);
      oacc[n] = __builtin_amdgcn_mfma_f32_16x16x32_bf16(pa, bv, oacc[n], 0, 0, 0);
    }
  }

  #pragma unroll
  for (int rr = 0; rr < 4; rr++) {
    int i = iq + rr;
    float inv = 1.0f / l_run[rr];
    #pragma unroll
    for (int n = 0; n < 4; n++)
      o[((long)(b * SMAX_ + i)) * D_ + h * 64 + n * 16 + l16] = (bf16)(oacc[n][rr] * inv);
  }
}

// ---------------------------------------------------------------------------
__global__ __launch_bounds__(256) void transpose_cvt(
    const float* __restrict__ src, bf16* __restrict__ dst,
    int Kk, int Nn, long srcL, long dstL)
{
  __shared__ float tile[32][33];
  const int tx = threadIdx.x, ty = threadIdx.y;
  const long n0 = (long)blockIdx.x * 32, k0 = (long)blockIdx.y * 32;
  src += (long)blockIdx.z * srcL;
  dst += (long)blockIdx.z * dstL;
  #pragma unroll
  for (int i = 0; i < 4; i++)
    tile[ty + i * 8][tx] = src[(k0 + ty + i * 8) * Nn + n0 + tx];
  __syncthreads();
  #pragma unroll
  for (int i = 0; i < 4; i++)
    dst[(n0 + ty + i * 8) * Kk + k0 + tx] = (bf16)tile[tx][ty + i * 8];
}

__global__ __launch_bounds__(256) void cvt_bf16(
    const float* __restrict__ src, bf16* __restrict__ dst, long n4)
{
  long i = (long)blockIdx.x * 256 + threadIdx.x;
  if (i >= n4) return;
  float4 v = ((const float4*)src)[i];
  bf16x4 o; o[0] = (bf16)v.x; o[1] = (bf16)v.y; o[2] = (bf16)v.z; o[3] = (bf16)v.w;
  ((bf16x4*)dst)[i] = o;
}

__global__ __launch_bounds__(256) void pack_bqkv(
    const float* __restrict__ bq, const float* __restrict__ bk,
    const float* __restrict__ bv, float* __restrict__ out)
{
  int i = blockIdx.x * 256 + threadIdx.x;
  if (i >= L_ * 3072) return;
  int l = i / 3072, c = i % 3072;
  float v = (c < 1024) ? bq[l * 1024 + c]
          : (c < 2048) ? bk[l * 1024 + c - 1024]
                       : bv[l * 1024 + c - 2048];
  out[i] = v;
}

__global__ __launch_bounds__(256) void embed_k(
    const int* __restrict__ ids, const float* __restrict__ emb,
    const float* __restrict__ pos, float* __restrict__ x)
{
  const int m = blockIdx.x, t = threadIdx.x;
  const int id = ids[m];
  const int s = m & (SMAX_ - 1);
  float4 e = ((const float4*)(emb + (long)id * D_))[t];
  float4 p = ((const float4*)(pos + (long)s * D_))[t];
  float4 rr; rr.x = e.x + p.x; rr.y = e.y + p.y; rr.z = e.z + p.z; rr.w = e.w + p.w;
  ((float4*)(x + (long)m * D_))[t] = rr;
}

__global__ __launch_bounds__(256) void rmsnorm_k(
    const float* __restrict__ x, const float* __restrict__ wgt,
    bf16* __restrict__ out)
{
  __shared__ float red[4];
  const int m = blockIdx.x, t = threadIdx.x;
  float4 v = ((const float4*)(x + (long)m * D_))[t];
  float ss = v.x * v.x + v.y * v.y + v.z * v.z + v.w * v.w;
  #pragma unroll
  for (int off = 1; off < 64; off <<= 1) ss += __shfl_xor(ss, off, 64);
  const int lane = t & 63, w = t >> 6;
  if (lane == 0) red[w] = ss;
  __syncthreads();
  float tot = red[0] + red[1] + red[2] + red[3];
  float rs = rsqrtf(tot * (1.0f / D_) + 1e-6f);
  float4 g = ((const float4*)wgt)[t];
  bf16x4 o;
  o[0] = (bf16)(v.x * rs * g.x); o[1] = (bf16)(v.y * rs * g.y);
  o[2] = (bf16)(v.z * rs * g.z); o[3] = (bf16)(v.w * rs * g.w);
  ((bf16x4*)(out + (long)m * D_))[t] = o;
}

// ---------------------------------------------------------------------------
extern "C" void kernel_launch(void* const* d_in, const int* in_sizes, int n_in,
                              void* d_out, int out_size, void* d_ws, size_t ws_size,
                              hipStream_t stream)
{
  const int*   ids = (const int*)d_in[0];
  const float* emb = (const float*)d_in[1];
  const float* pos = (const float*)d_in[2];
  const float* n1w = (const float*)d_in[3];
  const float* n2w = (const float*)d_in[4];
  const float* wq  = (const float*)d_in[5];
  const float* bq  = (const float*)d_in[6];
  const float* wk  = (const float*)d_in[7];
  const float* bk  = (const float*)d_in[8];
  const float* wv  = (const float*)d_in[9];
  const float* bv  = (const float*)d_in[10];
  const float* wo  = (const float*)d_in[11];
  const float* bo  = (const float*)d_in[12];
  const float* w1  = (const float*)d_in[13];
  const float* b1  = (const float*)d_in[14];
  const float* w2  = (const float*)d_in[15];
  const float* b2  = (const float*)d_in[16];
  const float* nfw = (const float*)d_in[17];

  char* p = (char*)d_ws;
  auto alloc = [&](size_t bytes) {
    char* rr = p; p += (bytes + 255) & ~(size_t)255; return rr;
  };
  bf16*  wqkv_t = (bf16*) alloc((size_t)L_ * 3 * 1024 * 1024 * 2);
  bf16*  wo_t   = (bf16*) alloc((size_t)L_ * 1024 * 1024 * 2);
  bf16*  w1_t   = (bf16*) alloc((size_t)L_ * 4096 * 1024 * 2);
  bf16*  w2_t   = (bf16*) alloc((size_t)L_ * 1024 * 4096 * 2);
  bf16*  emb_bf = (bf16*) alloc((size_t)V_ * D_ * 2);
  float* bqkv   = (float*)alloc((size_t)L_ * 3072 * 4);
  float* x      = (float*)alloc((size_t)M_ * D_ * 4);
  bf16*  hbuf   = (bf16*) alloc((size_t)M_ * D_ * 2);
  bf16*  qkv    = (bf16*) alloc((size_t)M_ * 3072 * 2);
  bf16*  obuf   = (bf16*) alloc((size_t)M_ * D_ * 2);
  bf16*  ff     = (bf16*) alloc((size_t)M_ * DFF_ * 2);

  const dim3 b32(32, 8, 1);
  transpose_cvt<<<dim3(32, 32, L_),  b32, 0, stream>>>(wq, wqkv_t,                1024, 1024, 1024 * 1024, 3 * 1024 * 1024);
  transpose_cvt<<<dim3(32, 32, L_),  b32, 0, stream>>>(wk, wqkv_t + 1024 * 1024,  1024, 1024, 1024 * 1024, 3 * 1024 * 1024);
  transpose_cvt<<<dim3(32, 32, L_),  b32, 0, stream>>>(wv, wqkv_t + 2*1024*1024,  1024, 1024, 1024 * 1024, 3 * 1024 * 1024);
  transpose_cvt<<<dim3(32, 32, L_),  b32, 0, stream>>>(wo, wo_t,                  1024, 1024, 1024 * 1024, 1024 * 1024);
  transpose_cvt<<<dim3(128, 32, L_), b32, 0, stream>>>(w1, w1_t,                  1024, 4096, 1024 * 4096, 4096 * 1024);
  transpose_cvt<<<dim3(32, 128, L_), b32, 0, stream>>>(w2, w2_t,                  4096, 1024, 4096 * 1024, 1024 * 4096);
  cvt_bf16<<<32000, 256, 0, stream>>>(emb, emb_bf, (long)V_ * D_ / 4);
  pack_bqkv<<<24, 256, 0, stream>>>(bq, bk, bv, bqkv);
  embed_k<<<M_, 256, 0, stream>>>(ids, emb, pos, x);

  for (int l = 0; l < L_; l++) {
    rmsnorm_k<<<M_, 256, 0, stream>>>(x, n1w + l * D_, hbuf);
    gemm_l2<64, 0><<<dim3(32 * 24), 256, 0, stream>>>(
        hbuf, wqkv_t + (size_t)l * 3 * 1024 * 1024, bqkv + l * 3072,
        nullptr, qkv, nullptr, 3072, 1024, 31, 5);
    attn_swa<<<B_ * H_ * (SMAX_ / 64), 256, 0, stream>>>(qkv, obuf);
    gemm_l2<64, 2><<<dim3(32 * 8), 256, 0, stream>>>(
        obuf, wo_t + (size_t)l * 1024 * 1024, bo + l * D_,
        x, nullptr, nullptr, 1024, 1024, 31, 5);
    rmsnorm_k<<<M_, 256, 0, stream>>>(x, n2w + l * D_, hbuf);
    gemm_l2<128, 1><<<dim3(16 * 32), 256, 0, stream>>>(
        hbuf, w1_t + (size_t)l * 4096 * 1024, b1 + l * DFF_,
        nullptr, ff, nullptr, 4096, 1024, 15, 4);
    gemm_l2<64, 2><<<dim3(32 * 8), 256, 0, stream>>>(
        ff, w2_t + (size_t)l * 1024 * 4096, b2 + l * D_,
        x, nullptr, nullptr, 1024, 4096, 31, 5);
  }
  rmsnorm_k<<<M_, 256, 0, stream>>>(x, nfw, hbuf);
  gemm_lm4<<<dim3(8 * (V_ / 256)), 512, 0, stream>>>(
      hbuf, emb_bf, (float*)d_out, V_);
}

// Round 10
// 596.730 us; speedup vs baseline: 1.1240x; 1.1240x over previous
//
#include <hip/hip_runtime.h>
#include <hip/hip_bf16.h>
#include <cstdint>

typedef __bf16 bf16;
typedef __bf16 bf16x8 __attribute__((ext_vector_type(8)));
typedef __bf16 bf16x4 __attribute__((ext_vector_type(4)));
typedef float  f32x4  __attribute__((ext_vector_type(4)));

constexpr int V_    = 32000;
constexpr int SMAX_ = 1024;
constexpr int D_    = 1024;
constexpr int H_    = 16;
constexpr int L_    = 2;
constexpr int DFF_  = 4096;
constexpr int WIN_  = 256;
constexpr int B_    = 2;
constexpr int M_    = B_ * SMAX_; // 2048

#define SBAR0_() __builtin_amdgcn_sched_barrier(0)
#define HWBAR_() { __builtin_amdgcn_s_barrier(); SBAR0_(); }
#define LGKM0_() { asm volatile("s_waitcnt lgkmcnt(0)" ::: "memory"); SBAR0_(); }
#define VM0_()   { asm volatile("s_waitcnt vmcnt(0)" ::: "memory"); SBAR0_(); }

// ---------------------------------------------------------------------------
// LM head: R8 gemm_lm3 pipeline (256x256, 8 waves 2Mx4N wave 128x64, BK=64,
// slot^=(row&7) 0-conflict layout, 2 LDS buffers) with SWAPPED-OPERAND MFMA:
// mfma(B,A) -> D maps m=lane&15, n=(lane>>4)*4+reg, so each thread's f32x4
// holds 4 consecutive COLUMNS -> epilogue is 32 nontemporal dwordx4 stores
// per thread (vs 128 scalar dwords), bypassing L2 (logits never re-read).
// ---------------------------------------------------------------------------
__global__ __launch_bounds__(512, 1) void gemm_lm5(
    const bf16* __restrict__ A, const bf16* __restrict__ BT,
    float* __restrict__ outf, int Nn)
{
  constexpr int KK = 1024, NT = 16;
  __shared__ __align__(16) bf16 ldsA[2][16384];   // 2 x 256 rows x 64
  __shared__ __align__(16) bf16 ldsB[2][16384];

  const int t = threadIdx.x, lane = t & 63, w = t >> 6;
  const int l16 = lane & 15, lh = lane >> 4;
  const int wm = w >> 2, wn = w & 3;              // 2M x 4N, wave 128x64

  const int nloc = gridDim.x >> 3;                // 1000/8 = 125
  const int wg = (blockIdx.x & 7) * nloc + (blockIdx.x >> 3);
  const long m0 = (long)(wg & 7) * 256;
  const long n0 = (long)(wg >> 3) * 256;

  auto STGA = [&](int c, int k0) {
    #pragma unroll
    for (int q = 0; q < 4; ++q) {
      int row = q * 64 + (t >> 3);
      int sl  = (t & 7) ^ (row & 7);
      const bf16* g = A + (m0 + row) * (long)KK + k0 + sl * 8;
      __builtin_amdgcn_global_load_lds(
          (const __attribute__((address_space(1))) uint32_t*)g,
          (__attribute__((address_space(3))) uint32_t*)(&ldsA[c][q * 4096 + t * 8]),
          16, 0, 0);
    }
  };
  auto STGB = [&](int c, int k0) {
    #pragma unroll
    for (int q = 0; q < 4; ++q) {
      int row = q * 64 + (t >> 3);
      int sl  = (t & 7) ^ (row & 7);
      const bf16* g = BT + (n0 + row) * (long)KK + k0 + sl * 8;
      __builtin_amdgcn_global_load_lds(
          (const __attribute__((address_space(1))) uint32_t*)g,
          (__attribute__((address_space(3))) uint32_t*)(&ldsB[c][q * 4096 + t * 8]),
          16, 0, 0);
    }
  };
  auto LDA = [&](int c, int mi, int ks) -> bf16x8 {
    int row = wm * 128 + mi * 16 + l16;
    int sl  = (ks * 4 + lh) ^ (row & 7);
    return *(const bf16x8*)(&ldsA[c][row * 64 + sl * 8]);
  };
  auto LDB = [&](int c, int ni, int ks) -> bf16x8 {
    int row = wn * 64 + ni * 16 + l16;
    int sl  = (ks * 4 + lh) ^ (row & 7);
    return *(const bf16x8*)(&ldsB[c][row * 64 + sl * 8]);
  };

  f32x4 acc[8][4] = {};
  bf16x8 a[8], b[4];

  STGA(0, 0); STGB(0, 0);
  int kNext = 64;

  for (int j = 0; j < NT; ++j) {
    const int c = j & 1;
    VM0_();
    HWBAR_();
    // ---- phase 0 (k-half 0) + stage tile j+1 ----
    #pragma unroll
    for (int mi = 0; mi < 8; ++mi) a[mi] = LDA(c, mi, 0);
    #pragma unroll
    for (int ni = 0; ni < 4; ++ni) b[ni] = LDB(c, ni, 0);
    STGA(c ^ 1, kNext); STGB(c ^ 1, kNext);
    LGKM0_();
    __builtin_amdgcn_s_setprio(1);
    #pragma unroll
    for (int mi = 0; mi < 8; ++mi)
      #pragma unroll
      for (int ni = 0; ni < 4; ++ni)
        acc[mi][ni] = __builtin_amdgcn_mfma_f32_16x16x32_bf16(b[ni], a[mi], acc[mi][ni], 0, 0, 0);
    __builtin_amdgcn_s_setprio(0);
    HWBAR_();
    // ---- phase 1 (k-half 1) ----
    #pragma unroll
    for (int mi = 0; mi < 8; ++mi) a[mi] = LDA(c, mi, 1);
    #pragma unroll
    for (int ni = 0; ni < 4; ++ni) b[ni] = LDB(c, ni, 1);
    LGKM0_();
    __builtin_amdgcn_s_setprio(1);
    #pragma unroll
    for (int mi = 0; mi < 8; ++mi)
      #pragma unroll
      for (int ni = 0; ni < 4; ++ni)
        acc[mi][ni] = __builtin_amdgcn_mfma_f32_16x16x32_bf16(b[ni], a[mi], acc[mi][ni], 0, 0, 0);
    __builtin_amdgcn_s_setprio(0);
    kNext += 64; if (kNext == KK) kNext = 0;
  }

  asm volatile("s_waitcnt vmcnt(0) lgkmcnt(0)" ::: "memory");
  // swapped D: row = m (lane&15), col = n (lh*4 + reg) -> float4 per thread
  #pragma unroll
  for (int mi = 0; mi < 8; ++mi) {
    long row = m0 + wm * 128 + mi * 16 + l16;
    #pragma unroll
    for (int ni = 0; ni < 4; ++ni) {
      long col = n0 + wn * 64 + ni * 16 + lh * 4;
      __builtin_nontemporal_store(acc[mi][ni], (f32x4*)(outf + row * Nn + col));
    }
  }
}

// ---------------------------------------------------------------------------
// Layer GEMMs: R8 gemm_l2 pipeline with swapped-operand MFMA + vectorized
// epilogues (bf16x4 / float4 stores, float4 bias loads).
// EPI: 0 bias->bf16, 1 bias+gelu->bf16, 2 bias+residual->f32, 3 ->f32
// ---------------------------------------------------------------------------
template<int BM, int EPI>
__global__ __launch_bounds__(256) void gemm_l2(
    const bf16* __restrict__ A, const bf16* __restrict__ BT,
    const float* __restrict__ bias, float* __restrict__ resid,
    bf16* __restrict__ outb, float* __restrict__ outf,
    int Nn, int Kk, int nbyMask, int nbyShift)
{
  constexpr int MR = BM / 32;
  constexpr int CA = BM / 32;
  __shared__ __align__(16) bf16 ldsA[2][BM * 64];
  __shared__ __align__(16) bf16 ldsB[2][8192];

  const int t = threadIdx.x, lane = t & 63, w = t >> 6;
  const int l16 = lane & 15, lh = lane >> 4;
  const int wm = w >> 1, wn = w & 1;

  const int nwg = gridDim.x, bid = blockIdx.x;
  const int nloc = nwg >> 3;
  const int wg = (bid & 7) * nloc + (bid >> 3);
  const long m0 = (long)(wg & nbyMask) * BM;
  const long n0 = (long)(wg >> nbyShift) * 128;

  auto STGA = [&](int c, int k0) {
    #pragma unroll
    for (int q = 0; q < CA; ++q) {
      int row = q * 32 + (t >> 3);
      int sl  = (t & 7) ^ (row & 7);
      const bf16* g = A + (m0 + row) * (long)Kk + k0 + sl * 8;
      __builtin_amdgcn_global_load_lds(
          (const __attribute__((address_space(1))) uint32_t*)g,
          (__attribute__((address_space(3))) uint32_t*)(&ldsA[c][q * 2048 + t * 8]),
          16, 0, 0);
    }
  };
  auto STGB = [&](int c, int k0) {
    #pragma unroll
    for (int q = 0; q < 4; ++q) {
      int row = q * 32 + (t >> 3);
      int sl  = (t & 7) ^ (row & 7);
      const bf16* g = BT + (n0 + row) * (long)Kk + k0 + sl * 8;
      __builtin_amdgcn_global_load_lds(
          (const __attribute__((address_space(1))) uint32_t*)g,
          (__attribute__((address_space(3))) uint32_t*)(&ldsB[c][q * 2048 + t * 8]),
          16, 0, 0);
    }
  };
  auto LDA = [&](int c, int mi, int ks) -> bf16x8 {
    int row = wm * (BM / 2) + mi * 16 + l16;
    int sl  = (ks * 4 + lh) ^ (row & 7);
    return *(const bf16x8*)(&ldsA[c][row * 64 + sl * 8]);
  };
  auto LDB = [&](int c, int ni, int ks) -> bf16x8 {
    int row = wn * 64 + ni * 16 + l16;
    int sl  = (ks * 4 + lh) ^ (row & 7);
    return *(const bf16x8*)(&ldsB[c][row * 64 + sl * 8]);
  };

  f32x4 acc[MR][4] = {};
  bf16x8 a[MR], b[4];

  STGA(0, 0); STGB(0, 0);
  int kNext = 64;

  const int NT = Kk >> 6;
  for (int j = 0; j < NT; ++j) {
    const int c = j & 1;
    VM0_();
    HWBAR_();
    #pragma unroll
    for (int mi = 0; mi < MR; ++mi) a[mi] = LDA(c, mi, 0);
    #pragma unroll
    for (int ni = 0; ni < 4; ++ni) b[ni] = LDB(c, ni, 0);
    STGA(c ^ 1, kNext); STGB(c ^ 1, kNext);
    LGKM0_();
    __builtin_amdgcn_s_setprio(1);
    #pragma unroll
    for (int mi = 0; mi < MR; ++mi)
      #pragma unroll
      for (int ni = 0; ni < 4; ++ni)
        acc[mi][ni] = __builtin_amdgcn_mfma_f32_16x16x32_bf16(b[ni], a[mi], acc[mi][ni], 0, 0, 0);
    __builtin_amdgcn_s_setprio(0);
    HWBAR_();
    #pragma unroll
    for (int mi = 0; mi < MR; ++mi) a[mi] = LDA(c, mi, 1);
    #pragma unroll
    for (int ni = 0; ni < 4; ++ni) b[ni] = LDB(c, ni, 1);
    LGKM0_();
    __builtin_amdgcn_s_setprio(1);
    #pragma unroll
    for (int mi = 0; mi < MR; ++mi)
      #pragma unroll
      for (int ni = 0; ni < 4; ++ni)
        acc[mi][ni] = __builtin_amdgcn_mfma_f32_16x16x32_bf16(b[ni], a[mi], acc[mi][ni], 0, 0, 0);
    __builtin_amdgcn_s_setprio(0);
    kNext += 64; if (kNext == Kk) kNext = 0;
  }

  // swapped D: row = m (lane&15), col = n (lh*4 + reg)
  #pragma unroll
  for (int mi = 0; mi < MR; ++mi) {
    long row = m0 + wm * (BM / 2) + mi * 16 + l16;
    #pragma unroll
    for (int ni = 0; ni < 4; ++ni) {
      long col = n0 + wn * 64 + ni * 16 + lh * 4;
      f32x4 v = acc[mi][ni];
      if (EPI == 3) {
        *(f32x4*)(outf + row * Nn + col) = v;
      } else {
        f32x4 bv = *(const f32x4*)(bias + col);
        v += bv;
        if (EPI == 0) {
          bf16x4 o;
          #pragma unroll
          for (int e = 0; e < 4; ++e) o[e] = (bf16)v[e];
          *(bf16x4*)(outb + row * Nn + col) = o;
        } else if (EPI == 1) {
          bf16x4 o;
          #pragma unroll
          for (int e = 0; e < 4; ++e) {
            float xx = v[e];
            o[e] = (bf16)(0.5f * xx * (1.0f + erff(xx * 0.70710678118654752f)));
          }
          *(bf16x4*)(outb + row * Nn + col) = o;
        } else { // EPI == 2
          f32x4 r = *(f32x4*)(resid + row * Nn + col);
          r += v;
          *(f32x4*)(resid + row * Nn + col) = r;
        }
      }
    }
  }
}

// ---------------------------------------------------------------------------
// Sliding-window causal flash attention (unchanged).
// ---------------------------------------------------------------------------
__global__ __launch_bounds__(256) void attn_swa(
    const bf16* __restrict__ qkv, bf16* __restrict__ o)
{
  constexpr int PADK = 72;
  constexpr int PADV = 40;
  __shared__ bf16 Qs[64 * PADK];
  __shared__ bf16 Ks[32 * PADK];
  __shared__ bf16 Vt[64 * PADV];
  __shared__ bf16 Ps[4][16 * PADV];

  const int bid = blockIdx.x;
  const int qb = bid & 15;
  const int h  = (bid >> 4) & 15;
  const int b  = bid >> 8;
  const int q0 = qb * 64;
  const int t = threadIdx.x, lane = t & 63, w = t >> 6;
  const int l16 = lane & 15, lh = lane >> 4;

  #pragma unroll
  for (int i = 0; i < 2; i++) {
    int e = t + i * 256;
    int row = e >> 3, cc = e & 7;
    uint4 g = *(const uint4*)(qkv + ((long)(b * SMAX_ + q0 + row)) * 3072 + h * 64 + cc * 8);
    *(uint4*)(Qs + row * PADK + cc * 8) = g;
  }
  __syncthreads();
  bf16x8 aq[2];
  const int qrow = w * 16 + l16;
  #pragma unroll
  for (int ks = 0; ks < 2; ks++)
    aq[ks] = *(const bf16x8*)(Qs + qrow * PADK + ks * 32 + lh * 8);

  float m_run[4], l_run[4];
  f32x4 oacc[4];
  #pragma unroll
  for (int rr = 0; rr < 4; rr++) { m_run[rr] = -1e30f; l_run[rr] = 0.0f; }
  #pragma unroll
  for (int n = 0; n < 4; n++) oacc[n] = (f32x4){0.f, 0.f, 0.f, 0.f};

  const int tlo = q0 - (WIN_ - 1);
  const int jlo = (tlo <= 0) ? 0 : (tlo & ~31);
  const int iq  = q0 + w * 16 + lh * 4;

  for (int j0 = jlo; j0 < q0 + 64; j0 += 32) {
    __syncthreads();
    {
      int row = t >> 3, cc = t & 7;
      long base = ((long)(b * SMAX_ + j0 + row)) * 3072 + h * 64 + cc * 8;
      uint4 gk = *(const uint4*)(qkv + base + 1024);
      *(uint4*)(Ks + row * PADK + cc * 8) = gk;
      bf16x8 vv = *(const bf16x8*)(qkv + base + 2048);
      #pragma unroll
      for (int j = 0; j < 8; j++)
        Vt[(cc * 8 + j) * PADV + row] = vv[j];
    }
    __syncthreads();

    f32x4 s[2] = {(f32x4){0.f,0.f,0.f,0.f}, (f32x4){0.f,0.f,0.f,0.f}};
    #pragma unroll
    for (int nt = 0; nt < 2; nt++)
      #pragma unroll
      for (int ks = 0; ks < 2; ks++) {
        bf16x8 bk = *(const bf16x8*)(Ks + (nt * 16 + l16) * PADK + ks * 32 + lh * 8);
        s[nt] = __builtin_amdgcn_mfma_f32_16x16x32_bf16(aq[ks], bk, s[nt], 0, 0, 0);
      }

    float sc[2][4];
    #pragma unroll
    for (int nt = 0; nt < 2; nt++)
      #pragma unroll
      for (int rr = 0; rr < 4; rr++) {
        int i = iq + rr;
        int j = j0 + nt * 16 + l16;
        float v = s[nt][rr] * 0.125f;
        bool ok = (j <= i) && (i - j < WIN_);
        sc[nt][rr] = ok ? v : -1e30f;
      }

    float pb[2][4], alpha[4];
    #pragma unroll
    for (int rr = 0; rr < 4; rr++) {
      float mt = fmaxf(sc[0][rr], sc[1][rr]);
      #pragma unroll
      for (int off = 1; off < 16; off <<= 1) mt = fmaxf(mt, __shfl_xor(mt, off, 64));
      float mn = fmaxf(m_run[rr], mt);
      float a = __expf(m_run[rr] - mn);
      m_run[rr] = mn; alpha[rr] = a;
      float p0 = __expf(sc[0][rr] - mn);
      float p1 = __expf(sc[1][rr] - mn);
      pb[0][rr] = p0; pb[1][rr] = p1;
      float ls = p0 + p1;
      #pragma unroll
      for (int off = 1; off < 16; off <<= 1) ls += __shfl_xor(ls, off, 64);
      l_run[rr] = l_run[rr] * a + ls;
    }
    #pragma unroll
    for (int n = 0; n < 4; n++)
      #pragma unroll
      for (int rr = 0; rr < 4; rr++) oacc[n][rr] *= alpha[rr];

    #pragma unroll
    for (int rr = 0; rr < 4; rr++) {
      int prow = lh * 4 + rr;
      Ps[w][prow * PADV + l16]      = (bf16)pb[0][rr];
      Ps[w][prow * PADV + 16 + l16] = (bf16)pb[1][rr];
    }
    __syncthreads();

    bf16x8 pa = *(const bf16x8*)(&Ps[w][l16 * PADV + lh * 8]);
    #pragma unroll
    for (int n = 0; n < 4; n++) {
      bf16x8 bv = *(const bf16x8*)(Vt + (n * 16 + l16) * PADV + lh * 8);
      oacc[n] = __builtin_amdgcn_mfma_f32_16x16x32_bf16(pa, bv, oacc[n], 0, 0, 0);
    }
  }

  #pragma unroll
  for (int rr = 0; rr < 4; rr++) {
    int i = iq + rr;
    float inv = 1.0f / l_run[rr];
    #pragma unroll
    for (int n = 0; n < 4; n++)
      o[((long)(b * SMAX_ + i)) * D_ + h * 64 + n * 16 + l16] = (bf16)(oacc[n][rr] * inv);
  }
}

// ---------------------------------------------------------------------------
__global__ __launch_bounds__(256) void transpose_cvt(
    const float* __restrict__ src, bf16* __restrict__ dst,
    int Kk, int Nn, long srcL, long dstL)
{
  __shared__ float tile[32][33];
  const int tx = threadIdx.x, ty = threadIdx.y;
  const long n0 = (long)blockIdx.x * 32, k0 = (long)blockIdx.y * 32;
  src += (long)blockIdx.z * srcL;
  dst += (long)blockIdx.z * dstL;
  #pragma unroll
  for (int i = 0; i < 4; i++)
    tile[ty + i * 8][tx] = src[(k0 + ty + i * 8) * Nn + n0 + tx];
  __syncthreads();
  #pragma unroll
  for (int i = 0; i < 4; i++)
    dst[(n0 + ty + i * 8) * Kk + k0 + tx] = (bf16)tile[tx][ty + i * 8];
}

__global__ __launch_bounds__(256) void cvt_bf16(
    const float* __restrict__ src, bf16* __restrict__ dst, long n4)
{
  long i = (long)blockIdx.x * 256 + threadIdx.x;
  if (i >= n4) return;
  float4 v = ((const float4*)src)[i];
  bf16x4 o; o[0] = (bf16)v.x; o[1] = (bf16)v.y; o[2] = (bf16)v.z; o[3] = (bf16)v.w;
  ((bf16x4*)dst)[i] = o;
}

__global__ __launch_bounds__(256) void pack_bqkv(
    const float* __restrict__ bq, const float* __restrict__ bk,
    const float* __restrict__ bv, float* __restrict__ out)
{
  int i = blockIdx.x * 256 + threadIdx.x;
  if (i >= L_ * 3072) return;
  int l = i / 3072, c = i % 3072;
  float v = (c < 1024) ? bq[l * 1024 + c]
          : (c < 2048) ? bk[l * 1024 + c - 1024]
                       : bv[l * 1024 + c - 2048];
  out[i] = v;
}

__global__ __launch_bounds__(256) void embed_k(
    const int* __restrict__ ids, const float* __restrict__ emb,
    const float* __restrict__ pos, float* __restrict__ x)
{
  const int m = blockIdx.x, t = threadIdx.x;
  const int id = ids[m];
  const int s = m & (SMAX_ - 1);
  float4 e = ((const float4*)(emb + (long)id * D_))[t];
  float4 p = ((const float4*)(pos + (long)s * D_))[t];
  float4 rr; rr.x = e.x + p.x; rr.y = e.y + p.y; rr.z = e.z + p.z; rr.w = e.w + p.w;
  ((float4*)(x + (long)m * D_))[t] = rr;
}

__global__ __launch_bounds__(256) void rmsnorm_k(
    const float* __restrict__ x, const float* __restrict__ wgt,
    bf16* __restrict__ out)
{
  __shared__ float red[4];
  const int m = blockIdx.x, t = threadIdx.x;
  float4 v = ((const float4*)(x + (long)m * D_))[t];
  float ss = v.x * v.x + v.y * v.y + v.z * v.z + v.w * v.w;
  #pragma unroll
  for (int off = 1; off < 64; off <<= 1) ss += __shfl_xor(ss, off, 64);
  const int lane = t & 63, w = t >> 6;
  if (lane == 0) red[w] = ss;
  __syncthreads();
  float tot = red[0] + red[1] + red[2] + red[3];
  float rs = rsqrtf(tot * (1.0f / D_) + 1e-6f);
  float4 g = ((const float4*)wgt)[t];
  bf16x4 o;
  o[0] = (bf16)(v.x * rs * g.x); o[1] = (bf16)(v.y * rs * g.y);
  o[2] = (bf16)(v.z * rs * g.z); o[3] = (bf16)(v.w * rs * g.w);
  ((bf16x4*)(out + (long)m * D_))[t] = o;
}

// ---------------------------------------------------------------------------
extern "C" void kernel_launch(void* const* d_in, const int* in_sizes, int n_in,
                              void* d_out, int out_size, void* d_ws, size_t ws_size,
                              hipStream_t stream)
{
  const int*   ids = (const int*)d_in[0];
  const float* emb = (const float*)d_in[1];
  const float* pos = (const float*)d_in[2];
  const float* n1w = (const float*)d_in[3];
  const float* n2w = (const float*)d_in[4];
  const float* wq  = (const float*)d_in[5];
  const float* bq  = (const float*)d_in[6];
  const float* wk  = (const float*)d_in[7];
  const float* bk  = (const float*)d_in[8];
  const float* wv  = (const float*)d_in[9];
  const float* bv  = (const float*)d_in[10];
  const float* wo  = (const float*)d_in[11];
  const float* bo  = (const float*)d_in[12];
  const float* w1  = (const float*)d_in[13];
  const float* b1  = (const float*)d_in[14];
  const float* w2  = (const float*)d_in[15];
  const float* b2  = (const float*)d_in[16];
  const float* nfw = (const float*)d_in[17];

  char* p = (char*)d_ws;
  auto alloc = [&](size_t bytes) {
    char* rr = p; p += (bytes + 255) & ~(size_t)255; return rr;
  };
  bf16*  wqkv_t = (bf16*) alloc((size_t)L_ * 3 * 1024 * 1024 * 2);
  bf16*  wo_t   = (bf16*) alloc((size_t)L_ * 1024 * 1024 * 2);
  bf16*  w1_t   = (bf16*) alloc((size_t)L_ * 4096 * 1024 * 2);
  bf16*  w2_t   = (bf16*) alloc((size_t)L_ * 1024 * 4096 * 2);
  bf16*  emb_bf = (bf16*) alloc((size_t)V_ * D_ * 2);
  float* bqkv   = (float*)alloc((size_t)L_ * 3072 * 4);
  float* x      = (float*)alloc((size_t)M_ * D_ * 4);
  bf16*  hbuf   = (bf16*) alloc((size_t)M_ * D_ * 2);
  bf16*  qkv    = (bf16*) alloc((size_t)M_ * 3072 * 2);
  bf16*  obuf   = (bf16*) alloc((size_t)M_ * D_ * 2);
  bf16*  ff     = (bf16*) alloc((size_t)M_ * DFF_ * 2);

  const dim3 b32(32, 8, 1);
  transpose_cvt<<<dim3(32, 32, L_),  b32, 0, stream>>>(wq, wqkv_t,                1024, 1024, 1024 * 1024, 3 * 1024 * 1024);
  transpose_cvt<<<dim3(32, 32, L_),  b32, 0, stream>>>(wk, wqkv_t + 1024 * 1024,  1024, 1024, 1024 * 1024, 3 * 1024 * 1024);
  transpose_cvt<<<dim3(32, 32, L_),  b32, 0, stream>>>(wv, wqkv_t + 2*1024*1024,  1024, 1024, 1024 * 1024, 3 * 1024 * 1024);
  transpose_cvt<<<dim3(32, 32, L_),  b32, 0, stream>>>(wo, wo_t,                  1024, 1024, 1024 * 1024, 1024 * 1024);
  transpose_cvt<<<dim3(128, 32, L_), b32, 0, stream>>>(w1, w1_t,                  1024, 4096, 1024 * 4096, 4096 * 1024);
  transpose_cvt<<<dim3(32, 128, L_), b32, 0, stream>>>(w2, w2_t,                  4096, 1024, 4096 * 1024, 1024 * 4096);
  cvt_bf16<<<32000, 256, 0, stream>>>(emb, emb_bf, (long)V_ * D_ / 4);
  pack_bqkv<<<24, 256, 0, stream>>>(bq, bk, bv, bqkv);
  embed_k<<<M_, 256, 0, stream>>>(ids, emb, pos, x);

  for (int l = 0; l < L_; l++) {
    rmsnorm_k<<<M_, 256, 0, stream>>>(x, n1w + l * D_, hbuf);
    gemm_l2<64, 0><<<dim3(32 * 24), 256, 0, stream>>>(
        hbuf, wqkv_t + (size_t)l * 3 * 1024 * 1024, bqkv + l * 3072,
        nullptr, qkv, nullptr, 3072, 1024, 31, 5);
    attn_swa<<<B_ * H_ * (SMAX_ / 64), 256, 0, stream>>>(qkv, obuf);
    gemm_l2<64, 2><<<dim3(32 * 8), 256, 0, stream>>>(
        obuf, wo_t + (size_t)l * 1024 * 1024, bo + l * D_,
        x, nullptr, nullptr, 1024, 1024, 31, 5);
    rmsnorm_k<<<M_, 256, 0, stream>>>(x, n2w + l * D_, hbuf);
    gemm_l2<128, 1><<<dim3(16 * 32), 256, 0, stream>>>(
        hbuf, w1_t + (size_t)l * 4096 * 1024, b1 + l * DFF_,
        nullptr, ff, nullptr, 4096, 1024, 15, 4);
    gemm_l2<64, 2><<<dim3(32 * 8), 256, 0, stream>>>(
        ff, w2_t + (size_t)l * 1024 * 4096, b2 + l * D_,
        x, nullptr, nullptr, 1024, 4096, 31, 5);
  }
  rmsnorm_k<<<M_, 256, 0, stream>>>(x, nfw, hbuf);
  gemm_lm5<<<dim3(8 * (V_ / 256)), 512, 0, stream>>>(
      hbuf, emb_bf, (float*)d_out, V_);
}